// Round 14
// baseline (250.294 us; speedup 1.0000x reference)
//
#include <hip/hip_runtime.h>
#include <math.h>

#define Bv   64
#define Nv   900
#define Mv   64
#define NCls 128
#define NCOLS (Nv + 1)          // 901 columns incl. dummy col 0
#define KREG 15                 // columns per lane: j = t + 64k, k=0..14
#define INFV 1000000000.0f
#define BIGV 1.0e18f            // sentinel for used/invalid slots

// uniform dynamic read (serial chain; only in the rare backtrack)
#define SEL15(arr, kidx, dst) do {            \
    int _s = arr[0];                          \
    _Pragma("unroll")                         \
    for (int _kk = 1; _kk < KREG; _kk++)      \
        _s = ((kidx) == _kk) ? arr[_kk] : _s; \
    (dst) = _s;                               \
} while (0)

// binary-tree select (depth 4). kidx may be PER-LANE. HW-verified R7-R10.
#define SELTREE15(arr, kidx, dst) do {                      \
    int _a0 = ((kidx) & 1) ? arr[1]  : arr[0];              \
    int _a1 = ((kidx) & 1) ? arr[3]  : arr[2];              \
    int _a2 = ((kidx) & 1) ? arr[5]  : arr[4];              \
    int _a3 = ((kidx) & 1) ? arr[7]  : arr[6];              \
    int _a4 = ((kidx) & 1) ? arr[9]  : arr[8];              \
    int _a5 = ((kidx) & 1) ? arr[11] : arr[10];             \
    int _a6 = ((kidx) & 1) ? arr[13] : arr[12];             \
    int _a7 = arr[14];          /* k==15 never occurs */    \
    int _b0 = ((kidx) & 2) ? _a1 : _a0;                     \
    int _b1 = ((kidx) & 2) ? _a3 : _a2;                     \
    int _b2 = ((kidx) & 2) ? _a5 : _a4;                     \
    int _b3 = ((kidx) & 2) ? _a7 : _a6;                     \
    int _c0 = ((kidx) & 4) ? _b1 : _b0;                     \
    int _c1 = ((kidx) & 4) ? _b3 : _b2;                     \
    (dst)   = ((kidx) & 8) ? _c1 : _c0;                     \
} while (0)

// uniform dynamic write (lane-targeted)
#define SET15(arr, kidx, val) do {            \
    _Pragma("unroll")                         \
    for (int _kk = 0; _kk < KREG; _kk++)      \
        if ((kidx) == _kk) arr[_kk] = (val);  \
} while (0)

// ---- order-preserving float <-> sortable u32 (bit-exact round trip) --------
__device__ __forceinline__ unsigned f2s(float f) {
    unsigned x = __float_as_uint(f);
    return x ^ ((unsigned)((int)x >> 31) | 0x80000000u);
}
__device__ __forceinline__ float s2f(unsigned s) {
    unsigned x = ((int)s < 0) ? (s ^ 0x80000000u) : ~s;
    return __uint_as_float(x);
}

// ---- wave64 min-reduce of packed (hi=sortable value, lo) via DPP -----------
// HW-verified R4/R7/R10. Lexicographic (value, lo); lo = (j<<7)|p[j] gives
// exact first-j tie-break (p is a function of j).
__device__ __forceinline__ void wave_min_pair(unsigned& hi, unsigned& lo) {
#define DPP_STEP(ctrl, rmask)                                                   \
    {                                                                           \
        unsigned ohi = (unsigned)__builtin_amdgcn_update_dpp(                   \
            (int)hi, (int)hi, ctrl, rmask, 0xf, false);                         \
        unsigned olo = (unsigned)__builtin_amdgcn_update_dpp(                   \
            (int)lo, (int)lo, ctrl, rmask, 0xf, false);                         \
        bool take = (ohi < hi) || (ohi == hi && olo < lo);                      \
        hi = take ? ohi : hi;                                                   \
        lo = take ? olo : lo;                                                   \
    }
    DPP_STEP(0x111, 0xf)   // row_shr:1
    DPP_STEP(0x112, 0xf)   // row_shr:2
    DPP_STEP(0x114, 0xf)   // row_shr:4
    DPP_STEP(0x118, 0xf)   // row_shr:8
    DPP_STEP(0x142, 0xa)   // row_bcast:15
    DPP_STEP(0x143, 0xc)   // row_bcast:31 -> lane 63 holds min
#undef DPP_STEP
    hi = (unsigned)__builtin_amdgcn_readlane((int)hi, 63);
    lo = (unsigned)__builtin_amdgcn_readlane((int)lo, 63);
}

// ---------------------------------------------------------------------------
// Kernel 1: cost matrix — R1 verbatim + ONE extra store: each thread also
// writes its value to CT[b][m][n] (m=t, row-major over n). The scattered
// store (64 lines/block) is async and costs ~3-5us — vs R2's +26us separate
// transpose kernel. CT=null (fallback) skips the store.
// ---------------------------------------------------------------------------
__global__ __launch_bounds__(64) void cost_kernel(
    const float* __restrict__ logits,   // [B,N,128]
    const float* __restrict__ corners,  // [B,N,8,3]
    const int*   __restrict__ labels,   // [B,64]
    const float* __restrict__ boxes,    // [B,64,7]
    float*       __restrict__ C,        // [B,N,64]
    float*       __restrict__ CT)       // [B,64,900] ws (or null)
{
    const int n = blockIdx.x, b = blockIdx.y, t = threadIdx.x;
    const long bn = (long)b * Nv + n;

    // softmax numerators: lane t handles classes 2t, 2t+1 (contiguous float2)
    const float2 l2 = ((const float2*)(logits + bn * NCls))[t];
    float e0 = expf(l2.x), e1 = expf(l2.y);

    __shared__ float probs[NCls];
    ((float2*)probs)[t] = make_float2(e0, e1);

    float s = e0 + e1;
    #pragma unroll
    for (int off = 1; off < 64; off <<= 1) s += __shfl_xor(s, off, 64);

    // center = mean over 8 corners
    const float* cp = corners + bn * 24;
    float cx = 0.f, cy = 0.f, cz = 0.f;
    if (t < 8) { cx = cp[3 * t]; cy = cp[3 * t + 1]; cz = cp[3 * t + 2]; }
    #pragma unroll
    for (int off = 1; off < 8; off <<= 1) {
        cx += __shfl_xor(cx, off, 64);
        cy += __shfl_xor(cy, off, 64);
        cz += __shfl_xor(cz, off, 64);
    }
    cx = __shfl(cx, 0, 64) * 0.125f;
    cy = __shfl(cy, 0, 64) * 0.125f;
    cz = __shfl(cz, 0, 64) * 0.125f;

    __syncthreads();   // probs visible

    int lbl = labels[b * Mv + t];
    float pm = probs[lbl] / s;
    const float* bx = boxes + ((long)b * Mv + t) * 7;
    float dx = cx - bx[0], dy = cy - bx[1], dz = cz - bx[2];
    float d = sqrtf(dx * dx + dy * dy + dz * dz);

    float val = 5.0f * d - pm;
    C[bn * Mv + t] = val;
    if (CT) CT[((size_t)b * Mv + t) * Nv + n] = val;   // bit-identical copy
}

// ---------------------------------------------------------------------------
// Kernel 2: LAPJV-style LSA — R10 structure VERBATIM except the two Phase C
// row-load sites. R13 closed every other axis; the ONE untested combination
// is CT-coalesced loads INSIDE the verified prefetch-cover structure:
//   gather: ~960 distinct lines -> ~480cy async TA work, only ~120 covered
//           by the update pass -> ~360cy exposed at the waitcnt.
//   CT row: ~30 lines (~15cy TA) + ~300cy L2 latency, ~120 covered
//           -> ~180cy exposed.  (R2/R3/R4/R11 all lacked this structure:
//           serial in-loop loads or broken scheduling — see their notes.)
// Loads stay RAW into crow (no folded arithmetic — R7/R8 lesson), identical
// masking, so the wait still sinks across the backedge. USECT=0 = R10 exact.
// ---------------------------------------------------------------------------
template <int USECT>
__global__ __launch_bounds__(64) void lsa_kernel(
    const float* __restrict__ C,    // [B, N, M] = [64,900,64]
    const float* __restrict__ CT,   // [B, M, N] = [64,64,900] ws (or null)
    float* __restrict__ outPred, float* __restrict__ outTgt)
{
    const int b = blockIdx.x;
    const int t = threadIdx.x;
    const float* cb  = C + (size_t)b * Nv * Mv;
    const float* ctb = USECT ? (CT + (size_t)b * Mv * Nv) : (const float*)0;

    // ---- Phase A: row argmin (lane t = row t+1); 4 ranges, deep unroll
    float mv0 = INFV, mv1 = INFV, mv2 = INFV, mv3 = INFV;
    int   mj0 = 0,    mj1 = 0,    mj2 = 0,    mj3 = 0;
    #pragma unroll 9
    for (int n = 0; n < 225; ++n) {
        float c0 = cb[(size_t)(n      ) * Mv + t];
        float c1 = cb[(size_t)(n + 225) * Mv + t];
        float c2 = cb[(size_t)(n + 450) * Mv + t];
        float c3 = cb[(size_t)(n + 675) * Mv + t];
        if (c0 < mv0) { mv0 = c0; mj0 = n;       }
        if (c1 < mv1) { mv1 = c1; mj1 = n + 225; }
        if (c2 < mv2) { mv2 = c2; mj2 = n + 450; }
        if (c3 < mv3) { mv3 = c3; mj3 = n + 675; }
    }
    float rowmin = mv0; int rown = mj0;
    if (mv1 < rowmin) { rowmin = mv1; rown = mj1; }
    if (mv2 < rowmin) { rowmin = mv2; rown = mj2; }
    if (mv3 < rowmin) { rowmin = mv3; rown = mj3; }

    float u_reg = rowmin;            // lane l holds u[l+1]
    const int jcol = rown + 1;       // column index in 1..900

    // ---- Phase B: duplicate detection (first occurrence wins)
    bool isdup = false;
    #pragma unroll
    for (int s = 1; s < 64; ++s) {
        int oj = __shfl(jcol, (t + 64 - s) & 63, 64);
        isdup |= (oj == jcol) && (s <= t);
    }
    unsigned long long pending = __ballot(isdup);

    int   p_reg[KREG], way_reg[KREG];
    float v_reg[KREG], minv[KREG], crow[KREG];
    #pragma unroll
    for (int k = 0; k < KREG; k++) { p_reg[k] = 0; way_reg[k] = 0; v_reg[k] = 0.f; }

    int rowcol = isdup ? 0 : jcol;   // lane i: column assigned to row i+1

    // scatter winners into distributed p[]
    #pragma unroll 8
    for (int i = 0; i < 64; ++i) {
        int jb = __shfl(jcol, i, 64);
        if (!((pending >> i) & 1ull) && t == (jb & 63))
            SET15(p_reg, jb >> 6, i + 1);
    }

    // ---- Phase C: Dijkstra phases for conflicted rows only
    while (pending) {
        const int i1v = __ffsll(pending);    // 1-based free row
        pending &= pending - 1;

        unsigned usedMask = (t == 0) ? 1u : 0u;   // dummy col 0 used
        unsigned long long rowMask = 0;
        #pragma unroll
        for (int k = 0; k < KREG; k++) minv[k] = INFV;

        int j0 = 0;
        int i0 = i1v;

        // initial row fetch; j==0 and j>=NCOLS slots get BIGV
        #pragma unroll
        for (int k = 0; k < KREG; k++) {
            int j = t + (k << 6);
            bool valid = (j >= 1 && j < NCOLS);
            if (USECT)
                crow[k] = valid ? ctb[(size_t)(i0 - 1) * Nv + (j - 1)] : BIGV;
            else
                crow[k] = valid ? cb[(((size_t)(j - 1)) << 6) + (i0 - 1)] : BIGV;
        }

        while (true) {
            rowMask |= 1ull << (i0 - 1);
            const int sl = __builtin_amdgcn_readfirstlane(i0 - 1);
            const float u_i0 = __int_as_float(
                __builtin_amdgcn_readlane(__float_as_int(u_reg), sl));

            // scan: sentinel-masked (R6-verified), 3-way split (R8-verified)
            float bv0 = INFV, bv1 = INFV, bv2 = INFV;
            int   bk0 = 0,    bk1 = 5,    bk2 = 10;
            #pragma unroll
            for (int k = 0; k < 5; k++) {
                float cur = (crow[k] - u_i0) - v_reg[k];
                if (cur < minv[k]) { minv[k] = cur; way_reg[k] = j0; }
                if (minv[k] < bv0) { bv0 = minv[k]; bk0 = k; }
            }
            #pragma unroll
            for (int k = 5; k < 10; k++) {
                float cur = (crow[k] - u_i0) - v_reg[k];
                if (cur < minv[k]) { minv[k] = cur; way_reg[k] = j0; }
                if (minv[k] < bv1) { bv1 = minv[k]; bk1 = k; }
            }
            #pragma unroll
            for (int k = 10; k < KREG; k++) {
                float cur = (crow[k] - u_i0) - v_reg[k];
                if (cur < minv[k]) { minv[k] = cur; way_reg[k] = j0; }
                if (minv[k] < bv2) { bv2 = minv[k]; bk2 = k; }
            }
            if (bv1 < bv0) { bv0 = bv1; bk0 = bk1; }
            if (bv2 < bv0) { bv0 = bv2; bk0 = bk2; }

            // fused packed reduce (R10-verified): delta, j1, inext at once
            int pcand; SELTREE15(p_reg, bk0, pcand);
            unsigned hi = f2s(bv0);
            unsigned lo = ((unsigned)(t + (bk0 << 6)) << 7) | (unsigned)pcand;
            wave_min_pair(hi, lo);
            const float delta = s2f(hi);
            const int   j1    = (int)(lo >> 7);
            const int   inext = (int)(lo & 0x7fu);

            const int k1 = j1 >> 6, l1 = j1 & 63;   // uniform (SGPR)

            // prefetch next row: RAW loads only (R7/R8 lesson) — vmcnt sinks
            // into the next scan, covered by the update pass below.
            const bool newbit = (t == l1);
            unsigned newUsed = usedMask | (newbit ? (1u << k1) : 0u);
            if (inext != 0) {
                const int src = inext - 1;
                #pragma unroll
                for (int k = 0; k < KREG; k++) {
                    int j = t + (k << 6);
                    bool valid = (j >= 1 && j < NCOLS) && !((newUsed >> k) & 1u);
                    if (USECT)
                        crow[k] = valid ? ctb[(size_t)src * Nv + (j - 1)] : BIGV;
                    else
                        crow[k] = valid ? cb[(((size_t)(j - 1)) << 6) + src] : BIGV;
                }
            }

            // dual/distance updates (reference order; latency cover)
            if ((rowMask >> t) & 1ull) u_reg += delta;
            #pragma unroll
            for (int k = 0; k < KREG; k++) {
                bool used  = (usedMask >> k) & 1u;
                bool isnew = newbit && (k == k1);
                v_reg[k] = used ? v_reg[k] - delta : v_reg[k];
                float mupd = used ? minv[k] : minv[k] - delta;
                minv[k] = isnew ? INFV : mupd;
            }
            usedMask = newUsed;

            j0 = j1;
            i0 = inext;
            if (i0 == 0) break;              // free column reached
        }

        // backtrack: reassign columns along augmenting path
        while (j0 != 0) {
            const int k0 = j0 >> 6, l0 = j0 & 63;
            int wtmp; SEL15(way_reg, k0, wtmp);
            const int jprev = __shfl(wtmp, l0, 64);
            int pv;
            if (jprev == 0) {
                pv = i1v;
            } else {
                int ptmp2; SEL15(p_reg, jprev >> 6, ptmp2);
                pv = __shfl(ptmp2, jprev & 63, 64);
            }
            if (t == l0) SET15(p_reg, k0, pv);
            if (t == pv - 1) rowcol = j0;    // maintain row->column mirror
            j0 = jprev;
        }
    }

    outPred[b * Mv + t] = (float)(rowcol - 1);
    outTgt[b * Mv + t]  = (float)t;
}

// ---------------------------------------------------------------------------
extern "C" void kernel_launch(void* const* d_in, const int* in_sizes, int n_in,
                              void* d_out, int out_size, void* d_ws, size_t ws_size,
                              hipStream_t stream)
{
    (void)in_sizes; (void)n_in; (void)out_size;

    const float* logits  = (const float*)d_in[0];   // [64,900,128] f32
    const float* corners = (const float*)d_in[1];   // [64,900,8,3] f32
    const int*   labels  = (const int*)  d_in[2];   // [64,64] i32
    const float* boxes   = (const float*)d_in[3];   // [64,64,7] f32

    float* out  = (float*)d_out;
    float* Cc   = out;                               // [64,900,64]
    float* pred = out + (size_t)Bv * Nv * Mv;        // [64,64] as f32
    float* tgt  = pred + (size_t)Bv * Mv;            // [64,64] as f32

    const size_t CT_BYTES = (size_t)Bv * Mv * Nv * sizeof(float);   // 14.75 MB
    if (d_ws != nullptr && ws_size >= CT_BYTES) {
        float* CT = (float*)d_ws;
        cost_kernel<<<dim3(Nv, Bv), 64, 0, stream>>>(logits, corners, labels, boxes, Cc, CT);
        lsa_kernel<1><<<Bv, 64, 0, stream>>>(Cc, CT, pred, tgt);
    } else {
        cost_kernel<<<dim3(Nv, Bv), 64, 0, stream>>>(logits, corners, labels, boxes, Cc, nullptr);
        lsa_kernel<0><<<Bv, 64, 0, stream>>>(Cc, nullptr, pred, tgt);
    }
}